// Round 8
// baseline (1523.778 us; speedup 1.0000x reference)
//
#include <hip/hip_runtime.h>
#include <hip/hip_bf16.h>

// RNN: emb[x] -> xw GEMM -> 256 sequential tanh steps -> fused FC.
// All matmuls in f16 MFMA (16x16x32) with f32 accumulate.
// B=64, T=256, H=E=512, O=4.
//
// R8: k2 restructured as 4 batch-groups x 4 M-quarters (16 WGs).
// Each WG: 16 batches (FULL N=16 MFMA tile), 128 W_hh rows -> 128 MFMAs
// per step (621 cyc/SIMD floor, 4x less than R6's 2483). W_hh quarter
// fits in registers (16 kc x 4 VGPR). Per step the 4 WGs of a group
// exchange h-quarters via global hG + ONE device-scope release-add /
// ONE acquire-poll on a per-group counter (R7 lesson: per-wave atomics'
// vmcnt(0) drains are the killer; __syncthreads already drains vmcnt,
// so a single tid0 release-add after it is enough). xw double-buffered
// in regs a full step ahead so no global load is near the fence.
// Overwrite safety: ctr[g] >= 32(t+1) implies every member finished
// step t, which implies it already READ hG slot (t+1)&1 from step t-1
// (reads happen in phase B of t-1, before its release of step t).

typedef _Float16 f16;
typedef _Float16 f16x4 __attribute__((ext_vector_type(4)));
typedef _Float16 f16x8 __attribute__((ext_vector_type(8)));
typedef float    f32x4 __attribute__((ext_vector_type(4)));

// d_ws layout (bytes)
#define XWB_OFF   0u
#define XWB_BYTES (64u*256u*512u*2u)            // 16 MB: xw + biases, f16 [B*T][H]
#define AWHH_OFF  (XWB_OFF + XWB_BYTES)         // 512 KB: W_hh A-operand fragments
#define BWIH_OFF  (AWHH_OFF + 512u*1024u)       // 512 KB: W_ih B-operand fragments
#define HG_OFF    (BWIH_OFF + 512u*1024u)       // 128 KB: h exchange [2][16][16][128] f16
#define HG_BYTES  (2u*16u*16u*128u*2u)
#define FLG_OFF   (HG_OFF + HG_BYTES)           // 16 B: 4 group counters

#define HSTRIDE 528     // f16 col stride: 264 dwords = 8 mod 32 -> even bank spread

// ---------------------------------------------------------------------------
// K0: pack W_hh (A-op layout) and W_ih (B-op layout) into fragment-linear
// f16: frag (kc, tile) at ((kc*32 + tile)*64 + lane)*8 f16.
// ---------------------------------------------------------------------------
__global__ __launch_bounds__(64) void k0_prep(const float* __restrict__ Whh,
                                              const float* __restrict__ Wih,
                                              f16* __restrict__ awhh,
                                              f16* __restrict__ bwih) {
    int id   = blockIdx.x;           // 0..1023
    int lane = threadIdx.x;          // 0..63
    bool is_ih = id >= 512;
    int lid = is_ih ? (id - 512) : id;       // = kc*32 + tile
    const float* src = is_ih ? Wih : Whh;
    f16* dst = is_ih ? bwih : awhh;
    int tile = lid & 31;
    int kc   = lid >> 5;
    int row  = tile * 16 + (lane & 15);
    int col0 = kc * 32 + (lane >> 4) * 8;
    const float* p = src + (size_t)row * 512 + col0;
    float4 v0 = *(const float4*)(p);
    float4 v1 = *(const float4*)(p + 4);
    f16x8 o;
    o[0] = (f16)v0.x; o[1] = (f16)v0.y; o[2] = (f16)v0.z; o[3] = (f16)v0.w;
    o[4] = (f16)v1.x; o[5] = (f16)v1.y; o[6] = (f16)v1.z; o[7] = (f16)v1.w;
    *(f16x8*)(dst + (size_t)lid * 512 + lane * 8) = o;
}

// ---------------------------------------------------------------------------
// K1: xwb[m][n] = sum_k emb[x[m]][k] * W_ih[n][k] + b_ih[n] + b_hh[n], f16.
// Double-buffered LDS staging; LDS-transpose epilogue for coalesced stores.
// ---------------------------------------------------------------------------
__global__ __launch_bounds__(256) void k1_xw(const int* __restrict__ x,
                                             const float* __restrict__ emb,
                                             const float* __restrict__ bih,
                                             const float* __restrict__ bhh,
                                             const f16* __restrict__ bwih,
                                             f16* __restrict__ xwb) {
    __shared__ f16 Bs[2][16384];     // 64 KB: double-buffered k-chunk of B frags
    int tid  = threadIdx.x;
    int wave = tid >> 6, lane = tid & 63;
    int quad = lane >> 4, l15 = lane & 15;
    int mrow0 = blockIdx.x * 64 + wave * 16;

    int arow_idx = x[mrow0 + l15];                  // gathered embedding row
    const float* arow = emb + (size_t)arow_idx * 512;

    f32x4 acc[32];
#pragma unroll
    for (int nt = 0; nt < 32; ++nt) acc[nt] = (f32x4){0.f, 0.f, 0.f, 0.f};

    float4 L[8];
    {
        const float4* s4 = (const float4*)bwih;
#pragma unroll
        for (int q = 0; q < 8; ++q) L[q] = s4[q * 256 + tid];
#pragma unroll
        for (int q = 0; q < 8; ++q) ((float4*)Bs[0])[q * 256 + tid] = L[q];
        const float4* s4b = (const float4*)(bwih + 16384);
#pragma unroll
        for (int q = 0; q < 8; ++q) L[q] = s4b[q * 256 + tid];
    }
    __syncthreads();

    for (int kc = 0; kc < 16; ++kc) {
        int cur = kc & 1;

        float4 a0 = *(const float4*)(arow + kc * 32 + quad * 8);
        float4 a1 = *(const float4*)(arow + kc * 32 + quad * 8 + 4);
        f16x8 af;
        af[0] = (f16)a0.x; af[1] = (f16)a0.y; af[2] = (f16)a0.z; af[3] = (f16)a0.w;
        af[4] = (f16)a1.x; af[5] = (f16)a1.y; af[6] = (f16)a1.z; af[7] = (f16)a1.w;

#pragma unroll
        for (int nt = 0; nt < 32; ++nt) {
            f16x8 bf = *(const f16x8*)(&Bs[cur][0] + nt * 512 + lane * 8);
            acc[nt] = __builtin_amdgcn_mfma_f32_16x16x32_f16(af, bf, acc[nt], 0, 0, 0);
        }

        if (kc < 15) {
#pragma unroll
            for (int q = 0; q < 8; ++q) ((float4*)Bs[cur ^ 1])[q * 256 + tid] = L[q];
        }
        __syncthreads();
        if (kc < 14) {
            const float4* s4 = (const float4*)(bwih + (size_t)(kc + 2) * 16384);
#pragma unroll
            for (int q = 0; q < 8; ++q) L[q] = s4[q * 256 + tid];
        }
    }
    __syncthreads();

    f16* trans = (f16*)Bs + (size_t)wave * 4224;
#pragma unroll
    for (int half = 0; half < 2; ++half) {
#pragma unroll
        for (int nt2 = 0; nt2 < 16; ++nt2) {
            int nt = half * 16 + nt2;
            int n = nt * 16 + l15;
            float bias = bih[n] + bhh[n];
#pragma unroll
            for (int r = 0; r < 4; ++r)
                trans[(quad * 4 + r) * 264 + nt2 * 16 + l15] =
                    (f16)(acc[nt][r] + bias);
        }
#pragma unroll
        for (int row = 0; row < 16; ++row) {
            f16x4 v = *(const f16x4*)(trans + row * 264 + lane * 4);
            *(f16x4*)(xwb + (size_t)(mrow0 + row) * 512 + half * 256 + lane * 4) = v;
        }
        __syncthreads();
    }
}

// ---------------------------------------------------------------------------
// K2 (split): 16 WGs x 512 thr. WG wg: group g=wg>>2 (batches g*16..g*16+15),
// quarter q=wg&3 (W_hh rows q*128..q*128+127). Wave w owns m-tile q*8+w.
// Per step: 16 MFMAs/wave (16 kc), A all in regs; B = h from LDS
// ([16 batch cols][512 rows], stride 528). Epilogue: 4 tanh/lane; own rows
// written to LDS next-buffer AND to global hG[slot]; one release-add on
// ctr[g] per WG; one acquire-poll; stage 3 peer quarters; barrier.
// After t=255: q==0 WGs compute the FC for their 16 batches.
// ---------------------------------------------------------------------------
__global__ __launch_bounds__(512, 2) void k2_split(const f16* __restrict__ awhh,
                                                   const f16* __restrict__ xwb,
                                                   const float* __restrict__ Wfc,
                                                   const float* __restrict__ bfc,
                                                   f16* __restrict__ hG,
                                                   unsigned* __restrict__ ctrs,
                                                   float* __restrict__ out) {
    __shared__ f16 hbuf[2][16 * HSTRIDE];   // 33792 B
    __shared__ float red[512];

    int tid  = threadIdx.x;
    int wave = tid >> 6, lane = tid & 63;
    int quad = lane >> 4, n = lane & 15;
    int wg   = blockIdx.x;
    int g    = wg >> 2, quarter = wg & 3;
    int grow0 = quarter * 128 + wave * 16;   // global row base of this wave's tile
    int tile  = quarter * 8 + wave;          // global m-tile index 0..31

    // --- all 16 kc A-frags in registers (64 VGPR) ---
    f16x8 areg[16];
#pragma unroll
    for (int kc = 0; kc < 16; ++kc)
        areg[kc] = *(const f16x8*)(awhh +
            ((size_t)(kc * 32 + tile) * 64 + lane) * 8);

    // --- zero both h buffers (h(0) = 0) ---
    {
        unsigned* hz = (unsigned*)&hbuf[0][0];
        for (int i = tid; i < 2 * 16 * HSTRIDE / 2; i += 512) hz[i] = 0u;
    }
    __syncthreads();

    // xw stream, double-buffered one step ahead
    const f16* xptr = xwb + ((size_t)(g * 16 + n) * 256) * 512 + grow0 + quad * 4;
    f16x4 xw_cur = *(const f16x4*)xptr;      // t = 0
    xptr += 512;

    int nn = tid >> 5;                        // staging: batch col 0..15
    int rb = (tid & 31) * 4;                  // staging: row-in-quarter 0..124

    const f16* cur = &hbuf[0][0];
    f16*       nxt = &hbuf[1][0];

    for (int t = 0; t < 256; ++t) {
        int s = (t + 1) & 1;

        // prefetch xw for t+1 (consumed next step -> full-step latency cover)
        f16x4 xw_nxt = {};
        if (t < 255) { xw_nxt = *(const f16x4*)xptr; xptr += 512; }

        // ---- phase A: own quarter GEMM ----
        f32x4 accA = (f32x4){0.f, 0.f, 0.f, 0.f};
#pragma unroll
        for (int kc = 0; kc < 8; ++kc) {
            f16x8 bf = *(const f16x8*)(cur + n * HSTRIDE + kc * 32 + quad * 8);
            accA = __builtin_amdgcn_mfma_f32_16x16x32_f16(areg[kc], bf, accA, 0, 0, 0);
        }
        f32x4 accB;
#pragma unroll
        for (int r = 0; r < 4; ++r) accB[r] = (float)xw_cur[r];
#pragma unroll
        for (int kc = 8; kc < 16; ++kc) {
            f16x8 bf = *(const f16x8*)(cur + n * HSTRIDE + kc * 32 + quad * 8);
            accB = __builtin_amdgcn_mfma_f32_16x16x32_f16(areg[kc], bf, accB, 0, 0, 0);
        }
        xw_cur = xw_nxt;

        // epilogue: 4 tanh per lane
        f16x4 hv;
#pragma unroll
        for (int r = 0; r < 4; ++r) {
            float z = accA[r] + accB[r];
            float e = __expf(2.f * z);           // bounded: |z| small
            hv[r] = (f16)((e - 1.f) * __builtin_amdgcn_rcpf(e + 1.f));
        }
        // own rows -> next LDS buffer and global exchange slot
        *(f16x4*)(nxt + n * HSTRIDE + grow0 + quad * 4) = hv;
        *(f16x4*)(hG + (((size_t)s * 16 + wg) * 16 + n) * 128 + wave * 16 + quad * 4) = hv;

        // ---- publish: barrier drains every wave's vmcnt; single release-add
        __syncthreads();
        if (tid == 0)
            (void)__hip_atomic_fetch_add(&ctrs[g], 8u, __ATOMIC_RELEASE,
                                         __HIP_MEMORY_SCOPE_AGENT);

        // ---- phase B: wait group, stage 3 peer quarters ----
        unsigned lim = 32u * (unsigned)(t + 1);
        while (__hip_atomic_load(&ctrs[g], __ATOMIC_ACQUIRE,
                                 __HIP_MEMORY_SCOPE_AGENT) < lim) { }

        f16x4 pv[3];
#pragma unroll
        for (int i = 1; i < 4; ++i) {
            int pq = (quarter + i) & 3;
            int peer = g * 4 + pq;
            pv[i - 1] = *(const f16x4*)(hG +
                (((size_t)s * 16 + peer) * 16 + nn) * 128 + rb);
        }
#pragma unroll
        for (int i = 1; i < 4; ++i) {
            int pq = (quarter + i) & 3;
            *(f16x4*)(nxt + nn * HSTRIDE + pq * 128 + rb) = pv[i - 1];
        }
        __syncthreads();
        f16* tmp = (f16*)cur; cur = nxt; nxt = tmp;
    }

    // ---- fused FC (one WG per group): h(256) is in `cur`, 16 cols ----
    if (quarter == 0) {
        int oo = tid >> 7;                // 0..3
        int fn = (tid >> 3) & 15;         // batch col
        int sg = tid & 7;                 // 8-way reduction split
        const f16* hrow = cur + fn * HSTRIDE;
        const float* wrow = Wfc + (size_t)oo * 512;
        float sacc = 0.f;
#pragma unroll
        for (int ii = 0; ii < 64; ++ii) {
            int i = sg * 64 + ii;
            sacc += (float)hrow[i] * wrow[i];
        }
        red[tid] = sacc;
        __syncthreads();
        if (tid < 64) {
            int oo2 = tid >> 4, n2 = tid & 15;
            float s2 = 0.f;
#pragma unroll
            for (int k = 0; k < 8; ++k) s2 += red[oo2 * 128 + n2 * 8 + k];
            out[(g * 16 + n2) * 4 + oo2] = s2 + bfc[oo2];
        }
    }
}

extern "C" void kernel_launch(void* const* d_in, const int* in_sizes, int n_in,
                              void* d_out, int out_size, void* d_ws, size_t ws_size,
                              hipStream_t stream) {
    const int*   x   = (const int*)d_in[0];
    const float* emb = (const float*)d_in[1];
    const float* Wih = (const float*)d_in[2];
    const float* Whh = (const float*)d_in[3];
    const float* bih = (const float*)d_in[4];
    const float* bhh = (const float*)d_in[5];
    const float* Wfc = (const float*)d_in[6];
    const float* bfc = (const float*)d_in[7];
    float* out = (float*)d_out;

    char* ws = (char*)d_ws;
    f16*      xwb  = (f16*)(ws + XWB_OFF);
    f16*      awhh = (f16*)(ws + AWHH_OFF);
    f16*      bwih = (f16*)(ws + BWIH_OFF);
    f16*      hG   = (f16*)(ws + HG_OFF);
    unsigned* ctrs = (unsigned*)(ws + FLG_OFF);

    // group counters must start at 0 (ws is poisoned before every launch)
    (void)hipMemsetAsync(ctrs, 0, 4 * sizeof(unsigned), stream);

    hipLaunchKernelGGL(k0_prep, dim3(1024), dim3(64),  0, stream, Whh, Wih, awhh, bwih);
    hipLaunchKernelGGL(k1_xw,   dim3(256),  dim3(256), 0, stream, x, emb, bih, bhh, bwih, xwb);
    hipLaunchKernelGGL(k2_split, dim3(16),  dim3(512), 0, stream,
                       awhh, xwb, Wfc, bfc, hG, ctrs, out);
}

// Round 9
// 566.648 us; speedup vs baseline: 2.6891x; 2.6891x over previous
//
#include <hip/hip_runtime.h>
#include <hip/hip_bf16.h>

// RNN: emb[x] -> xw GEMM -> 256 sequential tanh steps -> fused FC.
// All matmuls in f16 MFMA (16x16x32) with f32 accumulate.
// B=64, T=256, H=E=512, O=4.
//
// R9 = R6 (best known: single __syncthreads/step, h in 4 LDS cols stride
// 528, areg 12 kc + fragS 4 kc, dual 8-deep MFMA chains) + epilogue
// work-slicing: cols 4..15 of the D tile replicate cols 0..3, so lane
// (n,quad) finalizes ONLY tile g=n>>2, col c=n&3 (select acc[g], 4 tanh,
// one b64 write from all 64 lanes -> full coverage, no predication).
// xw: one 8-B load/lane for its own slice, double-buffered one step ahead.
// R7/R8 lesson (measured): per-step fences/cross-WG coherence traffic
// always lose; the 2483-cyc/step per-WG MFMA floor is structural.

typedef _Float16 f16;
typedef _Float16 f16x4 __attribute__((ext_vector_type(4)));
typedef _Float16 f16x8 __attribute__((ext_vector_type(8)));
typedef float    f32x4 __attribute__((ext_vector_type(4)));

// d_ws layout (bytes)
#define XWB_OFF   0u
#define XWB_BYTES (64u*256u*512u*2u)            // 16 MB: xw + biases, f16 [B*T][H]
#define AWHH_OFF  (XWB_OFF + XWB_BYTES)         // 512 KB: W_hh A-operand fragments
#define BWIH_OFF  (AWHH_OFF + 512u*1024u)       // 512 KB: W_ih B-operand fragments

#define HSTRIDE 528     // f16 col stride: 264 dwords = 8 mod 32 -> 2-way spread

// ---------------------------------------------------------------------------
// K0: pack W_hh (A-op layout) and W_ih (B-op layout) into fragment-linear
// f16: frag (kc, tile) at ((kc*32 + tile)*64 + lane)*8 f16.
// ---------------------------------------------------------------------------
__global__ __launch_bounds__(64) void k0_prep(const float* __restrict__ Whh,
                                              const float* __restrict__ Wih,
                                              f16* __restrict__ awhh,
                                              f16* __restrict__ bwih) {
    int id   = blockIdx.x;           // 0..1023
    int lane = threadIdx.x;          // 0..63
    bool is_ih = id >= 512;
    int lid = is_ih ? (id - 512) : id;       // = kc*32 + tile
    const float* src = is_ih ? Wih : Whh;
    f16* dst = is_ih ? bwih : awhh;
    int tile = lid & 31;
    int kc   = lid >> 5;
    int row  = tile * 16 + (lane & 15);
    int col0 = kc * 32 + (lane >> 4) * 8;
    const float* p = src + (size_t)row * 512 + col0;
    float4 v0 = *(const float4*)(p);
    float4 v1 = *(const float4*)(p + 4);
    f16x8 o;
    o[0] = (f16)v0.x; o[1] = (f16)v0.y; o[2] = (f16)v0.z; o[3] = (f16)v0.w;
    o[4] = (f16)v1.x; o[5] = (f16)v1.y; o[6] = (f16)v1.z; o[7] = (f16)v1.w;
    *(f16x8*)(dst + (size_t)lid * 512 + lane * 8) = o;
}

// ---------------------------------------------------------------------------
// K1: xwb[m][n] = sum_k emb[x[m]][k] * W_ih[n][k] + b_ih[n] + b_hh[n], f16.
// Double-buffered LDS staging; LDS-transpose epilogue for coalesced stores.
// ---------------------------------------------------------------------------
__global__ __launch_bounds__(256) void k1_xw(const int* __restrict__ x,
                                             const float* __restrict__ emb,
                                             const float* __restrict__ bih,
                                             const float* __restrict__ bhh,
                                             const f16* __restrict__ bwih,
                                             f16* __restrict__ xwb) {
    __shared__ f16 Bs[2][16384];     // 64 KB: double-buffered k-chunk of B frags
    int tid  = threadIdx.x;
    int wave = tid >> 6, lane = tid & 63;
    int quad = lane >> 4, l15 = lane & 15;
    int mrow0 = blockIdx.x * 64 + wave * 16;

    int arow_idx = x[mrow0 + l15];                  // gathered embedding row
    const float* arow = emb + (size_t)arow_idx * 512;

    f32x4 acc[32];
#pragma unroll
    for (int nt = 0; nt < 32; ++nt) acc[nt] = (f32x4){0.f, 0.f, 0.f, 0.f};

    float4 L[8];
    {
        const float4* s4 = (const float4*)bwih;
#pragma unroll
        for (int q = 0; q < 8; ++q) L[q] = s4[q * 256 + tid];
#pragma unroll
        for (int q = 0; q < 8; ++q) ((float4*)Bs[0])[q * 256 + tid] = L[q];
        const float4* s4b = (const float4*)(bwih + 16384);
#pragma unroll
        for (int q = 0; q < 8; ++q) L[q] = s4b[q * 256 + tid];
    }
    __syncthreads();

    for (int kc = 0; kc < 16; ++kc) {
        int cur = kc & 1;

        float4 a0 = *(const float4*)(arow + kc * 32 + quad * 8);
        float4 a1 = *(const float4*)(arow + kc * 32 + quad * 8 + 4);
        f16x8 af;
        af[0] = (f16)a0.x; af[1] = (f16)a0.y; af[2] = (f16)a0.z; af[3] = (f16)a0.w;
        af[4] = (f16)a1.x; af[5] = (f16)a1.y; af[6] = (f16)a1.z; af[7] = (f16)a1.w;

#pragma unroll
        for (int nt = 0; nt < 32; ++nt) {
            f16x8 bf = *(const f16x8*)(&Bs[cur][0] + nt * 512 + lane * 8);
            acc[nt] = __builtin_amdgcn_mfma_f32_16x16x32_f16(af, bf, acc[nt], 0, 0, 0);
        }

        if (kc < 15) {
#pragma unroll
            for (int q = 0; q < 8; ++q) ((float4*)Bs[cur ^ 1])[q * 256 + tid] = L[q];
        }
        __syncthreads();
        if (kc < 14) {
            const float4* s4 = (const float4*)(bwih + (size_t)(kc + 2) * 16384);
#pragma unroll
            for (int q = 0; q < 8; ++q) L[q] = s4[q * 256 + tid];
        }
    }
    __syncthreads();

    f16* trans = (f16*)Bs + (size_t)wave * 4224;
#pragma unroll
    for (int half = 0; half < 2; ++half) {
#pragma unroll
        for (int nt2 = 0; nt2 < 16; ++nt2) {
            int nt = half * 16 + nt2;
            int n = nt * 16 + l15;
            float bias = bih[n] + bhh[n];
#pragma unroll
            for (int r = 0; r < 4; ++r)
                trans[(quad * 4 + r) * 264 + nt2 * 16 + l15] =
                    (f16)(acc[nt][r] + bias);
        }
#pragma unroll
        for (int row = 0; row < 16; ++row) {
            f16x4 v = *(const f16x4*)(trans + row * 264 + lane * 4);
            *(f16x4*)(xwb + (size_t)(mrow0 + row) * 512 + half * 256 + lane * 4) = v;
        }
        __syncthreads();
    }
}

// ---------------------------------------------------------------------------
// K2: recurrence + fused FC. 16 WGs x 512 thr (8 waves, 2/SIMD).
// WG owns batches wg*4..wg*4+3. h in LDS: 4 cols, stride 528 f16.
// bf read col = n&3 -> 4-lane broadcast + 2-way bank spread (both free).
// Wave w owns m-tiles 4w..4w+3. W_hh: kc 0..11 in regs (unified VGPR/AGPR),
// kc 12..12+LKC-1 in LDS fragS, remainder streamed (LKC=4 -> none).
// Epilogue (R9): lane (n,quad) finalizes tile g=n>>2, col c=n&3 only:
// select acc[g], add xw (own 8-B slice), 4 tanh, b64 write by all lanes.
// ---------------------------------------------------------------------------
template<int LKC>
__global__ __launch_bounds__(512, 2) void k2_rnn(const f16* __restrict__ awhh,
                                                 const f16* __restrict__ xwb,
                                                 const float* __restrict__ Wfc,
                                                 const float* __restrict__ bfc,
                                                 float* __restrict__ out) {
    constexpr int SKC = 4 - LKC;                 // streamed kc count (kc 12+LKC..15)
    extern __shared__ char smem[];
    f16* fragS = (f16*)smem;                               // 32768*LKC B
    f16* hbuf  = (f16*)(smem + (size_t)32768 * LKC);       // 2*4*HSTRIDE f16 = 8448 B

    int tid  = threadIdx.x;
    int wave = tid >> 6, lane = tid & 63;
    int quad = lane >> 4, n = lane & 15;
    int c    = n & 3;                // h column this lane reads/finalizes
    int g    = n >> 2;               // tile (within wave) this lane finalizes
    int mtb  = wave * 4;

    // --- persistent A-frags, kc 0..11 ---
    f16x8 areg[4][12];
#pragma unroll
    for (int p = 0; p < 4; ++p)
#pragma unroll
        for (int kc = 0; kc < 12; ++kc)
            areg[p][kc] = *(const f16x8*)(awhh +
                ((size_t)(kc * 32 + mtb + p) * 64 + lane) * 8);

    // --- LDS-resident frags, kc 12..12+LKC-1 (per-wave private region) ---
#pragma unroll
    for (int p = 0; p < 4; ++p)
#pragma unroll
        for (int j = 0; j < LKC; ++j) {
            f16x8 v = *(const f16x8*)(awhh +
                ((size_t)((12 + j) * 32 + mtb + p) * 64 + lane) * 8);
            *(f16x8*)(fragS + (((mtb + p) * LKC + j) * 64 + lane) * 8) = v;
        }

    // --- zero h double-buffer (2*4*HSTRIDE f16 = 2112 dwords) ---
    {
        unsigned int* hz = (unsigned int*)hbuf;
        for (int i = tid; i < 2 * 4 * HSTRIDE / 2; i += 512) hz[i] = 0u;
    }
    __syncthreads();

    // per-lane epilogue offsets (own slice): row base i0, col c
    int i0 = (mtb + g) * 16 + quad * 4;
    int wofs = c * HSTRIDE + i0;                 // LDS write offset (f16)

    // xw stream: batch blk*4+c, rows i0..i0+3; double-buffered 1 step ahead
    const f16* xptr = xwb + ((size_t)(blockIdx.x * 4 + c) * 256) * 512 + i0;
    f16x4 xw_cur = *(const f16x4*)xptr;          // t = 0
    xptr += 512;

    for (int t = 0; t < 256; ++t) {
        const f16* hc = hbuf + (size_t)(t & 1) * 4 * HSTRIDE;
        f16*       hn = hbuf + (size_t)((t + 1) & 1) * 4 * HSTRIDE;

        // prefetch xw for t+1 (consumed next step -> full-step latency cover)
        f16x4 xw_nxt = {};
        if (t < 255) xw_nxt = *(const f16x4*)xptr;
        xptr += 512;

        // streamed A-frags (fallback only; LKC=4 -> none)
        f16x8 sst[SKC > 0 ? SKC : 1][4];
        if (SKC > 0) {
#pragma unroll
            for (int q = 0; q < SKC; ++q)
#pragma unroll
                for (int p = 0; p < 4; ++p)
                    sst[q][p] = *(const f16x8*)(awhh +
                        ((size_t)((12 + LKC + q) * 32 + mtb + p) * 64 + lane) * 8);
        }

        f32x4 accA[4], accB[4];
#pragma unroll
        for (int p = 0; p < 4; ++p) {
            accA[p] = (f32x4){0.f, 0.f, 0.f, 0.f};
            accB[p] = (f32x4){0.f, 0.f, 0.f, 0.f};
        }

        // kc 0..7 -> accA (8-deep chain), all-register A
#pragma unroll
        for (int kc = 0; kc < 8; ++kc) {
            f16x8 bf = *(const f16x8*)(hc + c * HSTRIDE + kc * 32 + quad * 8);
#pragma unroll
            for (int p = 0; p < 4; ++p)
                accA[p] = __builtin_amdgcn_mfma_f32_16x16x32_f16(
                    areg[p][kc], bf, accA[p], 0, 0, 0);
        }
        // kc 8..11 -> accB, register A
#pragma unroll
        for (int kc = 8; kc < 12; ++kc) {
            f16x8 bf = *(const f16x8*)(hc + c * HSTRIDE + kc * 32 + quad * 8);
#pragma unroll
            for (int p = 0; p < 4; ++p)
                accB[p] = __builtin_amdgcn_mfma_f32_16x16x32_f16(
                    areg[p][kc], bf, accB[p], 0, 0, 0);
        }
        // kc 12..12+LKC-1 -> accB, LDS A
#pragma unroll
        for (int j = 0; j < LKC; ++j) {
            int kc = 12 + j;
            f16x8 bf = *(const f16x8*)(hc + c * HSTRIDE + kc * 32 + quad * 8);
#pragma unroll
            for (int p = 0; p < 4; ++p) {
                f16x8 af = *(const f16x8*)(fragS +
                    (((mtb + p) * LKC + j) * 64 + lane) * 8);
                accB[p] = __builtin_amdgcn_mfma_f32_16x16x32_f16(
                    af, bf, accB[p], 0, 0, 0);
            }
        }
        // streamed tail (fallback only)
        if (SKC > 0) {
#pragma unroll
            for (int q = 0; q < SKC; ++q) {
                int kc = 12 + LKC + q;
                f16x8 bf = *(const f16x8*)(hc + c * HSTRIDE + kc * 32 + quad * 8);
#pragma unroll
                for (int p = 0; p < 4; ++p)
                    accB[p] = __builtin_amdgcn_mfma_f32_16x16x32_f16(
                        sst[q][p], bf, accB[p], 0, 0, 0);
            }
        }

        // R9 epilogue: select own tile g (cols 4..15 replicate 0..3, so the
        // 4 n-groups partition the work), 4 tanh/lane, one b64 write/lane.
        f32x4 za = (g == 0) ? accA[0] : (g == 1) ? accA[1]
                 : (g == 2) ? accA[2] : accA[3];
        f32x4 zb = (g == 0) ? accB[0] : (g == 1) ? accB[1]
                 : (g == 2) ? accB[2] : accB[3];
        f16x4 hv;
#pragma unroll
        for (int r = 0; r < 4; ++r) {
            float z = za[r] + zb[r] + (float)xw_cur[r];
            float e = __expf(2.f * z);           // bounded: |z| small
            hv[r] = (f16)((e - 1.f) * __builtin_amdgcn_rcpf(e + 1.f));
        }
        *(f16x4*)(hn + wofs) = hv;               // all 64 lanes: full coverage
        xw_cur = xw_nxt;

        __syncthreads();   // h(t+1) fully written before next step reads it
    }

    // ---- fused FC: h_T is in hbuf buffer 0, cols 0..3. fragS is dead.
    float* red = (float*)smem;           // 512 floats
    {
        int bb = tid >> 7;               // 0..3
        int oo = (tid >> 5) & 3;         // 0..3
        int sg = tid & 31;               // 0..31 -> 16 i each
        const f16* hrow = hbuf + bb * HSTRIDE;
        const float* wrow = Wfc + (size_t)oo * 512;
        float s = 0.f;
#pragma unroll
        for (int ii = 0; ii < 16; ++ii) {
            int i = sg * 16 + ii;
            s += (float)hrow[i] * wrow[i];
        }
        __syncthreads();                 // fragS reads all done before overwrite
        red[tid] = s;
    }
    __syncthreads();
    if (tid < 16) {
        int bb = tid >> 2, oo = tid & 3;
        float s = 0.f;
#pragma unroll
        for (int sg = 0; sg < 32; ++sg) s += red[(bb * 4 + oo) * 32 + sg];
        out[(blockIdx.x * 4 + bb) * 4 + oo] = s + bfc[oo];
    }
}

extern "C" void kernel_launch(void* const* d_in, const int* in_sizes, int n_in,
                              void* d_out, int out_size, void* d_ws, size_t ws_size,
                              hipStream_t stream) {
    const int*   x   = (const int*)d_in[0];
    const float* emb = (const float*)d_in[1];
    const float* Wih = (const float*)d_in[2];
    const float* Whh = (const float*)d_in[3];
    const float* bih = (const float*)d_in[4];
    const float* bhh = (const float*)d_in[5];
    const float* Wfc = (const float*)d_in[6];
    const float* bfc = (const float*)d_in[7];
    float* out = (float*)d_out;

    char* ws = (char*)d_ws;
    f16* xwb  = (f16*)(ws + XWB_OFF);
    f16* awhh = (f16*)(ws + AWHH_OFF);
    f16* bwih = (f16*)(ws + BWIH_OFF);

    hipLaunchKernelGGL(k0_prep, dim3(1024), dim3(64),  0, stream, Whh, Wih, awhh, bwih);
    hipLaunchKernelGGL(k1_xw,   dim3(256),  dim3(256), 0, stream, x, emb, bih, bhh, bwih, xwb);

    const int HB = 2 * 4 * HSTRIDE * 2;       // 8448 B
    const int LDS_BIG   = 32768 * 4 + HB;     // 139520
    const int LDS_SMALL = 32768 * 1 + HB;     // 41216
    int dev = 0;
    (void)hipGetDevice(&dev);
    int maxlds = 0;
    (void)hipDeviceGetAttribute(&maxlds, hipDeviceAttributeMaxSharedMemoryPerBlock, dev);
    bool big = maxlds >= LDS_BIG;
    if (big)
        big = (hipFuncSetAttribute((const void*)&k2_rnn<4>,
                                   hipFuncAttributeMaxDynamicSharedMemorySize,
                                   LDS_BIG) == hipSuccess);
    if (big) {
        hipLaunchKernelGGL(k2_rnn<4>, dim3(16), dim3(512), LDS_BIG, stream,
                           awhh, xwb, Wfc, bfc, out);
    } else {
        (void)hipFuncSetAttribute((const void*)&k2_rnn<1>,
                                  hipFuncAttributeMaxDynamicSharedMemorySize,
                                  LDS_SMALL);
        hipLaunchKernelGGL(k2_rnn<1>, dim3(16), dim3(512), LDS_SMALL, stream,
                           awhh, xwb, Wfc, bfc, out);
    }
}